// Round 7
// baseline (210.341 us; speedup 1.0000x reference)
//
#include <hip/hip_runtime.h>
#include <stdint.h>

#define GAS __attribute__((address_space(1)))
#define LAS __attribute__((address_space(3)))

typedef unsigned short u16;
typedef __attribute__((ext_vector_type(8))) __bf16 bf16x8;
typedef __attribute__((ext_vector_type(4))) float f32x4;
typedef __attribute__((ext_vector_type(4))) unsigned short u16x4;

#define SEQ 2048
#define WORD 1024
#define EMBED 128
#define NHEAD 16

__device__ __forceinline__ u16 f2b(float f) {
  return __builtin_bit_cast(u16, (__bf16)f);
}

// fragment-major offsets (within one head) ------------------------------
// Q/K layout: [rowtile=row>>4][kc=e>>5][lane][8]; lane = ((e>>3)&3)*16 + (row&15)
__device__ __forceinline__ long qfrag_off(int row, int e) {
  return ((((long)(row >> 4)) * 4 + (e >> 5)) * 64 + ((e >> 3) & 3) * 16 +
          (row & 15)) * 8 + (e & 7);
}
// V layout: [key>>5][es=er>>4][lane][8]; lane = ((key>>3)&3)*16 + (er&15)
__device__ __forceinline__ long vfrag_off(int er, int key) {
  return (((((long)(key >> 5)) * 8) + (er >> 4)) * 64 +
          ((key >> 3) & 3) * 16 + (er & 15)) * 8 + (key & 7);
}

// ---------------- cast x (fp32 -> bf16), 4 elems/thread ----------------
__global__ __launch_bounds__(256) void cast_x_kernel(const float* __restrict__ x,
                                                     u16* __restrict__ xb) {
  int i = (blockIdx.x * 256 + threadIdx.x) * 4;
  float4 v = *(const float4*)(x + i);
  ushort4 o;
  o.x = f2b(v.x); o.y = f2b(v.y); o.z = f2b(v.z); o.w = f2b(v.w);
  *(ushort4*)(xb + i) = o;
}

// ------------- transpose+cast: src[R][C] fp32 -> dst[C][R] bf16 --------
__global__ __launch_bounds__(256) void transpose_cast_kernel(
    const float* __restrict__ s0, const float* __restrict__ s1,
    const float* __restrict__ s2, u16* __restrict__ d0, u16* __restrict__ d1,
    u16* __restrict__ d2, int R, int C, long stride, int zsel) {
  __shared__ float tile[32][33];
  const float* s;
  u16* d;
  if (zsel) {
    int z = blockIdx.z;
    int wsel = z >> 4, hh = z & 15;
    s = (wsel == 0 ? s0 : wsel == 1 ? s1 : s2) + (long)hh * stride;
    d = (wsel == 0 ? d0 : wsel == 1 ? d1 : d2) + (long)hh * stride;
  } else {
    s = s0; d = d0;
  }
  int r0 = blockIdx.x * 32, c0 = blockIdx.y * 32;
  int tx = threadIdx.x & 31, ty = threadIdx.x >> 5;
#pragma unroll
  for (int i = 0; i < 4; ++i)
    tile[ty + i * 8][tx] = s[(long)(r0 + ty + i * 8) * C + c0 + tx];
  __syncthreads();
#pragma unroll
  for (int i = 0; i < 4; ++i)
    d[(long)(c0 + ty + i * 8) * R + r0 + tx] = f2b(tile[tx][ty + i * 8]);
}

// ---------------- generic 128x128-tile GEMM: C = (A·B^T + bias) * scale ----
// MODE: 0 = fp32 linear, 1 = u16 linear, 2 = u16 Q/K-fragment-major,
//       3 = u16 V-fragment-major. Modes 2/3: Cp is the head base;
//       rowbase/colbase = global (row,col) of this tile.
template <int MODE>
__device__ __forceinline__ void gemm128(const u16* __restrict__ A, const u16* __restrict__ B,
                                        void* __restrict__ Cp, int lda, int ldb, int ldc,
                                        int ksteps, const float* biasN, const float* biasM,
                                        float scale, int rowbase, int colbase) {
  __shared__ u16 lA[128 * 64];
  __shared__ u16 lB[128 * 64];
  const int tid = threadIdx.x;
  const int l = tid & 63, w = tid >> 6;
  const int quad = l >> 4, ln = l & 15;
  const int wm = w >> 1, wn = w & 1;
  f32x4 acc[4][4] = {};
  for (int ks = 0; ks < ksteps; ++ks) {
    const u16* Ak = A + ks * 64;
    const u16* Bk = B + ks * 64;
    __syncthreads();
#pragma unroll
    for (int i = 0; i < 4; ++i) {
      int idx = w * 256 + i * 64 + l;
      int r = idx >> 3, cp = idx & 7;
      int cg = cp ^ (r & 7);
      __builtin_amdgcn_global_load_lds((const GAS void*)(Ak + (long)r * lda + cg * 8),
                                       (LAS void*)(lA + (w * 256 + i * 64) * 8), 16, 0, 0);
      __builtin_amdgcn_global_load_lds((const GAS void*)(Bk + (long)r * ldb + cg * 8),
                                       (LAS void*)(lB + (w * 256 + i * 64) * 8), 16, 0, 0);
    }
    __syncthreads();
    bf16x8 af[2][4], bfv[2][4];
#pragma unroll
    for (int kc = 0; kc < 2; ++kc) {
#pragma unroll
      for (int i = 0; i < 4; ++i) {
        int c = kc * 4 + quad;
        int rm = wm * 64 + i * 16 + ln;
        af[kc][i] = *(const bf16x8*)(lA + rm * 64 + ((c ^ (rm & 7)) * 8));
        int rn = wn * 64 + i * 16 + ln;
        bfv[kc][i] = *(const bf16x8*)(lB + rn * 64 + ((c ^ (rn & 7)) * 8));
      }
    }
#pragma unroll
    for (int kc = 0; kc < 2; ++kc)
#pragma unroll
      for (int i = 0; i < 4; ++i)
#pragma unroll
        for (int j = 0; j < 4; ++j)
          acc[i][j] = __builtin_amdgcn_mfma_f32_16x16x32_bf16(af[kc][i], bfv[kc][j],
                                                              acc[i][j], 0, 0, 0);
  }
#pragma unroll
  for (int i = 0; i < 4; ++i) {
#pragma unroll
    for (int j = 0; j < 4; ++j) {
      int row0 = wm * 64 + i * 16 + quad * 4;
      int col = wn * 64 + j * 16 + ln;
      float bn = biasN ? biasN[col] : 0.f;
#pragma unroll
      for (int reg = 0; reg < 4; ++reg) {
        int row = row0 + reg;
        float bm = biasM ? biasM[row] : 0.f;
        float v = (acc[i][j][reg] + bn + bm) * scale;
        if constexpr (MODE == 0) {
          ((float*)Cp)[(long)row * ldc + col] = v;
        } else if constexpr (MODE == 1) {
          ((u16*)Cp)[(long)row * ldc + col] = f2b(v);
        } else if constexpr (MODE == 2) {
          ((u16*)Cp)[qfrag_off(rowbase + row, colbase + col)] = f2b(v);
        } else {
          ((u16*)Cp)[vfrag_off(rowbase + row, colbase + col)] = f2b(v);
        }
      }
    }
  }
}

// ---------------- fused QKV projection (z: 0=Q,1=K,2=V^T) ----------------
// Q and K written fragment-major (identical layout); V fragment-major for
// the PV B-operand. log2(e)/sqrt(E) folded into Q.
__global__ __launch_bounds__(256, 3) void qkv_gemm_kernel(
    const u16* __restrict__ xb, const u16* __restrict__ Wqt, const u16* __restrict__ Wkt,
    const u16* __restrict__ Wvt, const float* __restrict__ bq, const float* __restrict__ bk,
    const float* __restrict__ bv, u16* __restrict__ Qf, u16* __restrict__ Kf,
    u16* __restrict__ Vf) {
  const int t = blockIdx.x;
  const int h = blockIdx.y;
  const int which = blockIdx.z;
  const float qscale = 0.12753042123789493f;  // log2(e)/sqrt(128)
  if (which == 0) {
    gemm128<2>(xb + t * 128 * WORD, Wqt + h * EMBED * WORD,
               Qf + (long)h * 262144, WORD, WORD, 0,
               WORD / 64, bq + h * EMBED, nullptr, qscale, t * 128, 0);
  } else if (which == 1) {
    gemm128<2>(xb + t * 128 * WORD, Wkt + h * EMBED * WORD,
               Kf + (long)h * 262144, WORD, WORD, 0,
               WORD / 64, bk + h * EMBED, nullptr, 1.f, t * 128, 0);
  } else {
    // V^T[e][s]: rows = e (A = Wvt), cols = keys (B = x rows)
    gemm128<3>(Wvt + h * EMBED * WORD, xb + t * 128 * WORD,
               Vf + (long)h * 262144, WORD, WORD, 0,
               WORD / 64, nullptr, bv + h * EMBED, 1.f, 0, t * 128);
  }
}

// ---------------- flash attention: pure register streaming ----------------
// No LDS for K/V. Block = 256 thr = (2 row-groups wr of 32 q rows) x
// (2 key-groups wk of 1024 contiguous keys); grid 512 (head = bid&15 so an
// XCD's L2 holds ~2 heads' KV). Per 32-key iter: 8 kf + 8 vf coalesced
// dwordx4 loads with LINEAR addressing (no swizzle VALU), S^T = K.Q^T,
// exp2 -> P via tiny wave-private LDS, PV. Rotating 1-deep pipeline:
// kf(i+1) issued after S(i) (kf regs dead), vf(i+1) after PV(i); in-order
// vmcnt => consuming kf never drains the younger vf prefetch and vice
// versa. NO barriers in the loop -> waves drift, pipes overlap.
__global__ __launch_bounds__(256, 2) void attn_kernel(const u16* __restrict__ Qf,
                                                      const u16* __restrict__ Kf,
                                                      const u16* __restrict__ Vf,
                                                      u16* __restrict__ Zs) {
  __shared__ char smem[34304];  // loop: per-wave P (10 KB); epilogue: merge buf
  const int bid = blockIdx.x;
  const int h = bid & 15, qb = bid >> 4;  // qb: 64-row q tile, 0..31
  const int tid = threadIdx.x;
  const int l = tid & 63, w = tid >> 6, quad = l >> 4, ln = l & 15;
  const int wr = w >> 1, wk = w & 1;
  const u16* Qfh = Qf + (long)h * 262144;
  u16* Pw = (u16*)smem + w * 1280;  // [32 qrows][stride 40]

  // persistent Q fragments (B-operand of S^T = K.Q^T)
  bf16x8 qf[2][4];
#pragma unroll
  for (int rs = 0; rs < 2; ++rs)
#pragma unroll
    for (int kc = 0; kc < 4; ++kc)
      qf[rs][kc] = *(const bf16x8*)(Qfh + (((qb * 4 + wr * 2 + rs) * 4 + kc) * 64 + l) * 8);

  const __bf16 ov = (ln == 0) ? (__bf16)1.0f : (__bf16)0.0f;
  const bf16x8 onesf = {ov, ov, ov, ov, ov, ov, ov, ov};

  f32x4 oacc[2][8] = {};
  f32x4 lacc[2] = {};

  const u16* kp = Kf + (long)h * 262144 + wk * 131072 + l * 8;
  const u16* vp = Vf + (long)h * 262144 + wk * 131072 + l * 8;

  bf16x8 kf[8], vf[8];
#pragma unroll
  for (int t = 0; t < 8; ++t) kf[t] = *(const bf16x8*)(kp + t * 512);
#pragma unroll
  for (int es = 0; es < 8; ++es) vf[es] = *(const bf16x8*)(vp + es * 512);

  for (int i = 0; i < 32; ++i) {
    // ---- S^T = K.Q^T (2 ktiles x 4 e-chunks) ----
    f32x4 sacc[2][2] = {};
#pragma unroll
    for (int ns = 0; ns < 2; ++ns)
#pragma unroll
      for (int kc = 0; kc < 4; ++kc) {
        bf16x8 k8 = kf[ns * 4 + kc];
#pragma unroll
        for (int rs = 0; rs < 2; ++rs)
          sacc[rs][ns] = __builtin_amdgcn_mfma_f32_16x16x32_bf16(k8, qf[rs][kc],
                                                                 sacc[rs][ns], 0, 0, 0);
      }
    // kf regs dead -> prefetch kf(i+1) now (lands during exp2+PV)
    kp += 4096;
#pragma unroll
    for (int t = 0; t < 8; ++t) kf[t] = *(const bf16x8*)(kp + t * 512);
    // ---- P = exp2(S^T), C->A layout via wave-private LDS ----
#pragma unroll
    for (int rs = 0; rs < 2; ++rs)
#pragma unroll
      for (int ns = 0; ns < 2; ++ns) {
        u16x4 pk;
        pk.x = f2b(exp2f(sacc[rs][ns][0]));
        pk.y = f2b(exp2f(sacc[rs][ns][1]));
        pk.z = f2b(exp2f(sacc[rs][ns][2]));
        pk.w = f2b(exp2f(sacc[rs][ns][3]));
        *(u16x4*)(Pw + (rs * 16 + ln) * 40 + (ns * 4 + quad) * 4) = pk;
      }
    bf16x8 pa[2];
#pragma unroll
    for (int rs = 0; rs < 2; ++rs)
      pa[rs] = *(const bf16x8*)(Pw + (rs * 16 + ln) * 40 + quad * 8);
    // ---- O += P.V ; l += P.ones ----
#pragma unroll
    for (int es = 0; es < 8; ++es) {
      bf16x8 v8 = vf[es];
#pragma unroll
      for (int rs = 0; rs < 2; ++rs)
        oacc[rs][es] = __builtin_amdgcn_mfma_f32_16x16x32_bf16(pa[rs], v8,
                                                               oacc[rs][es], 0, 0, 0);
    }
#pragma unroll
    for (int rs = 0; rs < 2; ++rs)
      lacc[rs] = __builtin_amdgcn_mfma_f32_16x16x32_bf16(pa[rs], onesf, lacc[rs], 0, 0, 0);
    // vf regs dead -> prefetch vf(i+1) (lands during next S+exp2)
    vp += 4096;
#pragma unroll
    for (int es = 0; es < 8; ++es) vf[es] = *(const bf16x8*)(vp + es * 512);
  }
  // ---- merge wk=1 into wk=0 via LDS, divide by l, store ----
  __syncthreads();
  float* lO = (float*)smem;       // 64 x 132 fp32 = 33792 B
  float* lL = lO + 64 * 132;      // 64 fp32
  if (wk == 1) {
#pragma unroll
    for (int rs = 0; rs < 2; ++rs) {
#pragma unroll
      for (int es = 0; es < 8; ++es)
#pragma unroll
        for (int r = 0; r < 4; ++r)
          lO[(wr * 32 + rs * 16 + quad * 4 + r) * 132 + es * 16 + ln] = oacc[rs][es][r];
      if (ln == 0)
#pragma unroll
        for (int r = 0; r < 4; ++r)
          lL[wr * 32 + rs * 16 + quad * 4 + r] = lacc[rs][r];
    }
  }
  __syncthreads();
  if (wk == 0) {
#pragma unroll
    for (int rs = 0; rs < 2; ++rs)
#pragma unroll
      for (int r = 0; r < 4; ++r) {
        int grow = wr * 32 + rs * 16 + quad * 4 + r;
        float lsum = __shfl(lacc[rs][r], l & 48) + lL[grow];
        float rl = 1.f / lsum;
        int srow = qb * 64 + grow;
#pragma unroll
        for (int es = 0; es < 8; ++es) {
          float o = oacc[rs][es][r] + lO[grow * 132 + es * 16 + ln];
          Zs[(long)srow * (NHEAD * EMBED) + h * EMBED + es * 16 + ln] = f2b(o * rl);
        }
      }
  }
}

// ---------------- out = Zs · proj, split-K=8 into partials ----------------
__global__ __launch_bounds__(256, 2) void final_gemm_kernel(const u16* __restrict__ Zs,
                                                            const u16* __restrict__ projT,
                                                            float* __restrict__ pbuf) {
  const int t = blockIdx.x;
  const int kc = blockIdx.y;
  gemm128<0>(Zs + (long)t * 128 * (NHEAD * EMBED) + kc * 256, projT + kc * 256,
             pbuf + (long)kc * SEQ * EMBED + t * 128 * EMBED,
             NHEAD * EMBED, NHEAD * EMBED, EMBED, 4, nullptr, nullptr, 1.f, 0, 0);
}

__global__ __launch_bounds__(256) void reduce_kernel(const float* __restrict__ pbuf,
                                                     float* __restrict__ out) {
  int i = (blockIdx.x * 256 + threadIdx.x) * 4;
  float4 s = {0.f, 0.f, 0.f, 0.f};
#pragma unroll
  for (int kc = 0; kc < 8; ++kc) {
    float4 v = *(const float4*)(pbuf + (long)kc * SEQ * EMBED + i);
    s.x += v.x; s.y += v.y; s.z += v.z; s.w += v.w;
  }
  *(float4*)(out + i) = s;
}

extern "C" void kernel_launch(void* const* d_in, const int* in_sizes, int n_in,
                              void* d_out, int out_size, void* d_ws, size_t ws_size,
                              hipStream_t stream) {
  const float* x    = (const float*)d_in[0];
  const float* Wq   = (const float*)d_in[1];
  const float* bq   = (const float*)d_in[2];
  const float* Wk   = (const float*)d_in[3];
  const float* bk   = (const float*)d_in[4];
  const float* Wv   = (const float*)d_in[5];
  const float* bv   = (const float*)d_in[6];
  const float* proj = (const float*)d_in[7];
  float* out = (float*)d_out;

  char* ws = (char*)d_ws;
  u16* xb    = (u16*)(ws);                      // 2048x1024 bf16       (4 MiB)
  u16* Wqt   = (u16*)(ws + (4L << 20));         // [16][128][1024]      (4 MiB)
  u16* Wkt   = (u16*)(ws + (8L << 20));         //                      (4 MiB)
  u16* Wvt   = (u16*)(ws + (12L << 20));        //                      (4 MiB)
  u16* projT = (u16*)(ws + (16L << 20));        // [128][2048]          (0.5 MiB)
  u16* Qf    = (u16*)(ws + (17L << 20));        // Q fragment-major     (8 MiB)
  u16* Kf    = (u16*)(ws + (26L << 20));        // K fragment-major     (8 MiB)
  u16* Vf    = (u16*)(ws + (35L << 20));        // V fragment-major     (8 MiB)
  u16* Zs    = (u16*)(ws + (44L << 20));        // [2048][2048]         (8 MiB)
  float* pbuf = (float*)(ws);                   // [8][2048][128] fp32  (8 MiB, aliased)

  cast_x_kernel<<<dim3(SEQ * WORD / 1024), dim3(256), 0, stream>>>(x, xb);
  transpose_cast_kernel<<<dim3(WORD / 32, EMBED / 32, 48), dim3(256), 0, stream>>>(
      Wq, Wk, Wv, Wqt, Wkt, Wvt, WORD, EMBED, (long)WORD * EMBED, 1);
  transpose_cast_kernel<<<dim3(SEQ / 32, EMBED / 32, 1), dim3(256), 0, stream>>>(
      proj, nullptr, nullptr, projT, nullptr, nullptr, SEQ, EMBED, 0, 0);

  qkv_gemm_kernel<<<dim3(16, NHEAD, 3), dim3(256), 0, stream>>>(
      xb, Wqt, Wkt, Wvt, bq, bk, bv, Qf, Kf, Vf);

  attn_kernel<<<dim3(512), dim3(256), 0, stream>>>(Qf, Kf, Vf, Zs);

  final_gemm_kernel<<<dim3(16, 8), dim3(256), 0, stream>>>(Zs, projT, pbuf);
  reduce_kernel<<<dim3(SEQ * EMBED / 1024), dim3(256), 0, stream>>>(pbuf, out);
}

// Round 8
// 207.042 us; speedup vs baseline: 1.0159x; 1.0159x over previous
//
#include <hip/hip_runtime.h>
#include <stdint.h>

#define GAS __attribute__((address_space(1)))
#define LAS __attribute__((address_space(3)))

typedef unsigned short u16;
typedef __attribute__((ext_vector_type(8))) __bf16 bf16x8;
typedef __attribute__((ext_vector_type(4))) float f32x4;
typedef __attribute__((ext_vector_type(4))) unsigned short u16x4;

#define SEQ 2048
#define WORD 1024
#define EMBED 128
#define NHEAD 16

__device__ __forceinline__ u16 f2b(float f) {
  return __builtin_bit_cast(u16, (__bf16)f);
}

// fragment-major offsets (within one head) ------------------------------
// Q/K layout: [rowtile=row>>4][kc=e>>5][lane][8]; lane = ((e>>3)&3)*16 + (row&15)
__device__ __forceinline__ long qfrag_off(int row, int e) {
  return ((((long)(row >> 4)) * 4 + (e >> 5)) * 64 + ((e >> 3) & 3) * 16 +
          (row & 15)) * 8 + (e & 7);
}
// V layout: [key>>5][es=er>>4][lane][8]; lane = ((key>>3)&3)*16 + (er&15)
__device__ __forceinline__ long vfrag_off(int er, int key) {
  return (((((long)(key >> 5)) * 8) + (er >> 4)) * 64 +
          ((key >> 3) & 3) * 16 + (er & 15)) * 8 + (key & 7);
}

// ---------------- fused prep: cast x + all transposes, ONE launch ----------
// flat grid: [0,2048)   : cast x fp32->bf16 (1024 elems/block)
//            [2048,8192): QKV weight transpose tiles (48 z * 128 tiles)
//            [8192,8448): proj transpose tiles (256)
__global__ __launch_bounds__(256) void prep_kernel(
    const float* __restrict__ x, const float* __restrict__ Wq,
    const float* __restrict__ Wk, const float* __restrict__ Wv,
    const float* __restrict__ proj, u16* __restrict__ xb, u16* __restrict__ Wqt,
    u16* __restrict__ Wkt, u16* __restrict__ Wvt, u16* __restrict__ projT) {
  int b = blockIdx.x;
  if (b < 2048) {
    int i = b * 1024 + threadIdx.x * 4;
    float4 v = *(const float4*)(x + i);
    ushort4 o;
    o.x = f2b(v.x); o.y = f2b(v.y); o.z = f2b(v.z); o.w = f2b(v.w);
    *(ushort4*)(xb + i) = o;
    return;
  }
  __shared__ float tile[32][33];
  const float* s;
  u16* d;
  int R, r0, c0;
  if (b < 8192) {
    int idx = b - 2048;
    int z = idx >> 7, t2 = idx & 127;
    int wsel = z >> 4, hh = z & 15;
    long off = (long)hh * WORD * EMBED;
    s = (wsel == 0 ? Wq : wsel == 1 ? Wk : Wv) + off;
    d = (wsel == 0 ? Wqt : wsel == 1 ? Wkt : Wvt) + off;
    R = WORD;
    r0 = (t2 & 31) * 32;
    c0 = (t2 >> 5) * 32;
  } else {
    int idx = b - 8192;
    s = proj; d = projT;
    R = SEQ;                       // proj is [2048][128]
    r0 = (idx & 63) * 32;
    c0 = (idx >> 6) * 32;
  }
  int tx = threadIdx.x & 31, ty = threadIdx.x >> 5;
#pragma unroll
  for (int i = 0; i < 4; ++i)
    tile[ty + i * 8][tx] = s[(long)(r0 + ty + i * 8) * EMBED + c0 + tx];
  __syncthreads();
#pragma unroll
  for (int i = 0; i < 4; ++i)
    d[(long)(c0 + ty + i * 8) * R + r0 + tx] = f2b(tile[tx][ty + i * 8]);
}

// ---------------- generic 128x128-tile GEMM: C = (A·B^T + bias) * scale ----
// MODE: 0 = fp32 linear, 1 = u16 linear, 2 = u16 Q/K-fragment-major,
//       3 = u16 V-fragment-major.
template <int MODE>
__device__ __forceinline__ void gemm128(const u16* __restrict__ A, const u16* __restrict__ B,
                                        void* __restrict__ Cp, int lda, int ldb, int ldc,
                                        int ksteps, const float* biasN, const float* biasM,
                                        float scale, int rowbase, int colbase) {
  __shared__ u16 lA[128 * 64];
  __shared__ u16 lB[128 * 64];
  const int tid = threadIdx.x;
  const int l = tid & 63, w = tid >> 6;
  const int quad = l >> 4, ln = l & 15;
  const int wm = w >> 1, wn = w & 1;
  f32x4 acc[4][4] = {};
  for (int ks = 0; ks < ksteps; ++ks) {
    const u16* Ak = A + ks * 64;
    const u16* Bk = B + ks * 64;
    __syncthreads();
#pragma unroll
    for (int i = 0; i < 4; ++i) {
      int idx = w * 256 + i * 64 + l;
      int r = idx >> 3, cp = idx & 7;
      int cg = cp ^ (r & 7);
      __builtin_amdgcn_global_load_lds((const GAS void*)(Ak + (long)r * lda + cg * 8),
                                       (LAS void*)(lA + (w * 256 + i * 64) * 8), 16, 0, 0);
      __builtin_amdgcn_global_load_lds((const GAS void*)(Bk + (long)r * ldb + cg * 8),
                                       (LAS void*)(lB + (w * 256 + i * 64) * 8), 16, 0, 0);
    }
    __syncthreads();
    bf16x8 af[2][4], bfv[2][4];
#pragma unroll
    for (int kc = 0; kc < 2; ++kc) {
#pragma unroll
      for (int i = 0; i < 4; ++i) {
        int c = kc * 4 + quad;
        int rm = wm * 64 + i * 16 + ln;
        af[kc][i] = *(const bf16x8*)(lA + rm * 64 + ((c ^ (rm & 7)) * 8));
        int rn = wn * 64 + i * 16 + ln;
        bfv[kc][i] = *(const bf16x8*)(lB + rn * 64 + ((c ^ (rn & 7)) * 8));
      }
    }
#pragma unroll
    for (int kc = 0; kc < 2; ++kc)
#pragma unroll
      for (int i = 0; i < 4; ++i)
#pragma unroll
        for (int j = 0; j < 4; ++j)
          acc[i][j] = __builtin_amdgcn_mfma_f32_16x16x32_bf16(af[kc][i], bfv[kc][j],
                                                              acc[i][j], 0, 0, 0);
  }
#pragma unroll
  for (int i = 0; i < 4; ++i) {
#pragma unroll
    for (int j = 0; j < 4; ++j) {
      int row0 = wm * 64 + i * 16 + quad * 4;
      int col = wn * 64 + j * 16 + ln;
      float bn = biasN ? biasN[col] : 0.f;
#pragma unroll
      for (int reg = 0; reg < 4; ++reg) {
        int row = row0 + reg;
        float bm = biasM ? biasM[row] : 0.f;
        float v = (acc[i][j][reg] + bn + bm) * scale;
        if constexpr (MODE == 0) {
          ((float*)Cp)[(long)row * ldc + col] = v;
        } else if constexpr (MODE == 1) {
          ((u16*)Cp)[(long)row * ldc + col] = f2b(v);
        } else if constexpr (MODE == 2) {
          ((u16*)Cp)[qfrag_off(rowbase + row, colbase + col)] = f2b(v);
        } else {
          ((u16*)Cp)[vfrag_off(rowbase + row, colbase + col)] = f2b(v);
        }
      }
    }
  }
}

// ---------------- fused QKV projection (z: 0=Q,1=K,2=V^T) ----------------
__global__ __launch_bounds__(256, 3) void qkv_gemm_kernel(
    const u16* __restrict__ xb, const u16* __restrict__ Wqt, const u16* __restrict__ Wkt,
    const u16* __restrict__ Wvt, const float* __restrict__ bq, const float* __restrict__ bk,
    const float* __restrict__ bv, u16* __restrict__ Qf, u16* __restrict__ Kf,
    u16* __restrict__ Vf) {
  const int t = blockIdx.x;
  const int h = blockIdx.y;
  const int which = blockIdx.z;
  const float qscale = 0.12753042123789493f;  // log2(e)/sqrt(128)
  if (which == 0) {
    gemm128<2>(xb + t * 128 * WORD, Wqt + h * EMBED * WORD,
               Qf + (long)h * 262144, WORD, WORD, 0,
               WORD / 64, bq + h * EMBED, nullptr, qscale, t * 128, 0);
  } else if (which == 1) {
    gemm128<2>(xb + t * 128 * WORD, Wkt + h * EMBED * WORD,
               Kf + (long)h * 262144, WORD, WORD, 0,
               WORD / 64, bk + h * EMBED, nullptr, 1.f, t * 128, 0);
  } else {
    gemm128<3>(Wvt + h * EMBED * WORD, xb + t * 128 * WORD,
               Vf + (long)h * 262144, WORD, WORD, 0,
               WORD / 64, nullptr, bv + h * EMBED, 1.f, 0, t * 128);
  }
}

// ---------------- flash attention: register streaming, 4-way key split ----
// Block = 512 thr = 8 waves = (2 row-groups wr of 32 q rows) x (4 key-groups
// wk of 512 contiguous keys). Grid 512 (32 qtiles x 16 heads); 1 block/CU
// resident = 8 waves/CU = 2/SIMD. Per-wave KV traffic halves vs r7:
// 512 keys x 512 B = 256 KB -> 2 MB/CU through L1-return (~14 us).
// Loop body identical to r7 (proven): rotating kf/vf register prefetch,
// linear addressing, no in-loop barriers. Epilogue merges 4 partials.
__global__ __launch_bounds__(512, 2) void attn_kernel(const u16* __restrict__ Qf,
                                                      const u16* __restrict__ Kf,
                                                      const u16* __restrict__ Vf,
                                                      u16* __restrict__ Zs) {
  __shared__ char smem[34304];  // loop: 8 waves x 2560 B P; epilogue: merge buf
  const int bid = blockIdx.x;
  const int h = bid & 15, qb = bid >> 4;  // qb: 64-row q tile, 0..31
  const int tid = threadIdx.x;
  const int l = tid & 63, w = tid >> 6, quad = l >> 4, ln = l & 15;
  const int wr = w >> 2, wk = w & 3;
  const u16* Qfh = Qf + (long)h * 262144;
  u16* Pw = (u16*)smem + w * 1280;  // [32 qrows][stride 40]

  // persistent Q fragments (B-operand of S^T = K.Q^T)
  bf16x8 qf[2][4];
#pragma unroll
  for (int rs = 0; rs < 2; ++rs)
#pragma unroll
    for (int kc = 0; kc < 4; ++kc)
      qf[rs][kc] = *(const bf16x8*)(Qfh + (((qb * 4 + wr * 2 + rs) * 4 + kc) * 64 + l) * 8);

  const __bf16 ov = (ln == 0) ? (__bf16)1.0f : (__bf16)0.0f;
  const bf16x8 onesf = {ov, ov, ov, ov, ov, ov, ov, ov};

  f32x4 oacc[2][8] = {};
  f32x4 lacc[2] = {};

  // wk's 512-key stream: K = 32 rowtiles (65536 u16), V = 16 key-blocks
  const u16* kp = Kf + (long)h * 262144 + wk * 65536 + l * 8;
  const u16* vp = Vf + (long)h * 262144 + wk * 65536 + l * 8;
  const u16* kp4 = kp + 2048;  // imm-offset range split (13-bit signed)
  const u16* vp4 = vp + 2048;

  bf16x8 kf[8], vf[8];
#pragma unroll
  for (int t = 0; t < 4; ++t) kf[t] = *(const bf16x8*)(kp + t * 512);
#pragma unroll
  for (int t = 0; t < 4; ++t) kf[t + 4] = *(const bf16x8*)(kp4 + t * 512);
#pragma unroll
  for (int t = 0; t < 4; ++t) vf[t] = *(const bf16x8*)(vp + t * 512);
#pragma unroll
  for (int t = 0; t < 4; ++t) vf[t + 4] = *(const bf16x8*)(vp4 + t * 512);

  for (int i = 0; i < 16; ++i) {
    // ---- S^T = K.Q^T (2 ktiles x 4 e-chunks); kf[ns*4+kc] ----
    f32x4 sacc[2][2] = {};
#pragma unroll
    for (int ns = 0; ns < 2; ++ns)
#pragma unroll
      for (int kc = 0; kc < 4; ++kc) {
        bf16x8 k8 = kf[ns * 4 + kc];
#pragma unroll
        for (int rs = 0; rs < 2; ++rs)
          sacc[rs][ns] = __builtin_amdgcn_mfma_f32_16x16x32_bf16(k8, qf[rs][kc],
                                                                 sacc[rs][ns], 0, 0, 0);
      }
    // kf regs dead -> prefetch kf(i+1) (lands during exp2+PV)
    kp += 4096; kp4 += 4096;
#pragma unroll
    for (int t = 0; t < 4; ++t) kf[t] = *(const bf16x8*)(kp + t * 512);
#pragma unroll
    for (int t = 0; t < 4; ++t) kf[t + 4] = *(const bf16x8*)(kp4 + t * 512);
    // ---- P = exp2(S^T), C->A layout via wave-private LDS ----
#pragma unroll
    for (int rs = 0; rs < 2; ++rs)
#pragma unroll
      for (int ns = 0; ns < 2; ++ns) {
        u16x4 pk;
        pk.x = f2b(exp2f(sacc[rs][ns][0]));
        pk.y = f2b(exp2f(sacc[rs][ns][1]));
        pk.z = f2b(exp2f(sacc[rs][ns][2]));
        pk.w = f2b(exp2f(sacc[rs][ns][3]));
        *(u16x4*)(Pw + (rs * 16 + ln) * 40 + (ns * 4 + quad) * 4) = pk;
      }
    bf16x8 pa[2];
#pragma unroll
    for (int rs = 0; rs < 2; ++rs)
      pa[rs] = *(const bf16x8*)(Pw + (rs * 16 + ln) * 40 + quad * 8);
    // ---- O += P.V ; l += P.ones ----
#pragma unroll
    for (int es = 0; es < 8; ++es) {
      bf16x8 v8 = vf[es];
#pragma unroll
      for (int rs = 0; rs < 2; ++rs)
        oacc[rs][es] = __builtin_amdgcn_mfma_f32_16x16x32_bf16(pa[rs], v8,
                                                               oacc[rs][es], 0, 0, 0);
    }
#pragma unroll
    for (int rs = 0; rs < 2; ++rs)
      lacc[rs] = __builtin_amdgcn_mfma_f32_16x16x32_bf16(pa[rs], onesf, lacc[rs], 0, 0, 0);
    // vf regs dead -> prefetch vf(i+1) (lands during next S+exp2)
    vp += 4096; vp4 += 4096;
#pragma unroll
    for (int t = 0; t < 4; ++t) vf[t] = *(const bf16x8*)(vp + t * 512);
#pragma unroll
    for (int t = 0; t < 4; ++t) vf[t + 4] = *(const bf16x8*)(vp4 + t * 512);
  }
  // ---- merge 4 key-split partials (no-max softmax: plain sums) ----
  __syncthreads();
  float* lO = (float*)smem;       // 64 x 132 fp32 = 33792 B
  float* lL = lO + 64 * 132;      // 64 fp32
  for (int st = 3; st >= 1; --st) {
    if (wk == st) {
#pragma unroll
      for (int rs = 0; rs < 2; ++rs) {
#pragma unroll
        for (int es = 0; es < 8; ++es)
#pragma unroll
          for (int r = 0; r < 4; ++r) {
            int idx = (wr * 32 + rs * 16 + quad * 4 + r) * 132 + es * 16 + ln;
            if (st == 3) lO[idx] = oacc[rs][es][r];
            else lO[idx] += oacc[rs][es][r];
          }
        if (ln == 0)
#pragma unroll
          for (int r = 0; r < 4; ++r) {
            int row = wr * 32 + rs * 16 + quad * 4 + r;
            if (st == 3) lL[row] = lacc[rs][r];
            else lL[row] += lacc[rs][r];
          }
      }
    }
    __syncthreads();
  }
  if (wk == 0) {
#pragma unroll
    for (int rs = 0; rs < 2; ++rs)
#pragma unroll
      for (int r = 0; r < 4; ++r) {
        int grow = wr * 32 + rs * 16 + quad * 4 + r;
        float lsum = __shfl(lacc[rs][r], l & 48) + lL[grow];
        float rl = 1.f / lsum;
        int srow = qb * 64 + grow;
#pragma unroll
        for (int es = 0; es < 8; ++es) {
          float o = oacc[rs][es][r] + lO[grow * 132 + es * 16 + ln];
          Zs[(long)srow * (NHEAD * EMBED) + h * EMBED + es * 16 + ln] = f2b(o * rl);
        }
      }
  }
}

// ---------------- out = Zs · proj, split-K=8 into partials ----------------
__global__ __launch_bounds__(256, 2) void final_gemm_kernel(const u16* __restrict__ Zs,
                                                            const u16* __restrict__ projT,
                                                            float* __restrict__ pbuf) {
  const int t = blockIdx.x;
  const int kc = blockIdx.y;
  gemm128<0>(Zs + (long)t * 128 * (NHEAD * EMBED) + kc * 256, projT + kc * 256,
             pbuf + (long)kc * SEQ * EMBED + t * 128 * EMBED,
             NHEAD * EMBED, NHEAD * EMBED, EMBED, 4, nullptr, nullptr, 1.f, 0, 0);
}

__global__ __launch_bounds__(256) void reduce_kernel(const float* __restrict__ pbuf,
                                                     float* __restrict__ out) {
  int i = (blockIdx.x * 256 + threadIdx.x) * 4;
  float4 s = {0.f, 0.f, 0.f, 0.f};
#pragma unroll
  for (int kc = 0; kc < 8; ++kc) {
    float4 v = *(const float4*)(pbuf + (long)kc * SEQ * EMBED + i);
    s.x += v.x; s.y += v.y; s.z += v.z; s.w += v.w;
  }
  *(float4*)(out + i) = s;
}

extern "C" void kernel_launch(void* const* d_in, const int* in_sizes, int n_in,
                              void* d_out, int out_size, void* d_ws, size_t ws_size,
                              hipStream_t stream) {
  const float* x    = (const float*)d_in[0];
  const float* Wq   = (const float*)d_in[1];
  const float* bq   = (const float*)d_in[2];
  const float* Wk   = (const float*)d_in[3];
  const float* bk   = (const float*)d_in[4];
  const float* Wv   = (const float*)d_in[5];
  const float* bv   = (const float*)d_in[6];
  const float* proj = (const float*)d_in[7];
  float* out = (float*)d_out;

  char* ws = (char*)d_ws;
  u16* xb    = (u16*)(ws);                      // 2048x1024 bf16       (4 MiB)
  u16* Wqt   = (u16*)(ws + (4L << 20));         // [16][128][1024]      (4 MiB)
  u16* Wkt   = (u16*)(ws + (8L << 20));         //                      (4 MiB)
  u16* Wvt   = (u16*)(ws + (12L << 20));        //                      (4 MiB)
  u16* projT = (u16*)(ws + (16L << 20));        // [128][2048]          (0.5 MiB)
  u16* Qf    = (u16*)(ws + (17L << 20));        // Q fragment-major     (8 MiB)
  u16* Kf    = (u16*)(ws + (26L << 20));        // K fragment-major     (8 MiB)
  u16* Vf    = (u16*)(ws + (35L << 20));        // V fragment-major     (8 MiB)
  u16* Zs    = (u16*)(ws + (44L << 20));        // [2048][2048]         (8 MiB)
  float* pbuf = (float*)(ws);                   // [8][2048][128] fp32  (8 MiB, aliased)

  prep_kernel<<<dim3(8448), dim3(256), 0, stream>>>(x, Wq, Wk, Wv, proj, xb, Wqt,
                                                    Wkt, Wvt, projT);

  qkv_gemm_kernel<<<dim3(16, NHEAD, 3), dim3(256), 0, stream>>>(
      xb, Wqt, Wkt, Wvt, bq, bk, bv, Qf, Kf, Vf);

  attn_kernel<<<dim3(512), dim3(512), 0, stream>>>(Qf, Kf, Vf, Zs);

  final_gemm_kernel<<<dim3(16, 8), dim3(256), 0, stream>>>(Zs, projT, pbuf);
  reduce_kernel<<<dim3(SEQ * EMBED / 1024), dim3(256), 0, stream>>>(pbuf, out);
}